// Round 9
// baseline (209.682 us; speedup 1.0000x reference)
//
#include <hip/hip_runtime.h>
#include <hip/hip_fp16.h>
#include <math.h>

// Instant-NGP forward (round 9):
//   pre:    ONE kernel: table f32 -> fp16-pair (4B/entry); x -> float4;
//           weights -> bf16 B^T tables.
//   encode: TWO points per thread (2i, 2i+1) -> 8 independent uint4 gathers in
//           flight per thread (2x memory-level parallelism vs round 5).
//           dim0 hash prime == 1 => corner pair inside one aligned 16B block
//           (4 fp16-pair entries) for 75% of ix; masked scalar fixup else.
//   mlp:    MFMA bf16 16x16x32; 4 waves/block, 64 points/wave.

constexpr int      LVLS   = 16;
constexpr uint32_t TSIZE  = 1u << 19;
constexpr uint32_t TMASK  = TSIZE - 1u;
constexpr uint32_t PRIME1 = 2654435761u;
constexpr uint32_t PRIME2 = 805459861u;

struct ResArr { float v[LVLS]; };  // res[l] - 1.0f

typedef __attribute__((ext_vector_type(8))) short short8v;  // 8 bf16
typedef __attribute__((ext_vector_type(4))) float float4v;  // MFMA acc

__device__ inline ushort f2bf(float f) {          // RNE f32 -> bf16
    uint u = __float_as_uint(f);
    u += 0x7fffu + ((u >> 16) & 1u);
    return (ushort)(u >> 16);
}

__device__ inline float2 h2f(uint u) {
    __half2 h = *reinterpret_cast<__half2*>(&u);
    return __half22float2(h);
}

__device__ inline uint pick4(const uint4& b, uint j) {
    const uint lo = (j & 1u) ? b.y : b.x;
    const uint hi = (j & 1u) ? b.w : b.z;
    return (j & 2u) ? hi : lo;
}

// ---------------- pre: fp16 table + x pack + weight prep (one kernel) ------
__global__ __launch_bounds__(256)
void ingp_pre(const float* __restrict__ table, uint* __restrict__ tab16,
              const float* __restrict__ x, float4* __restrict__ x4,
              const float* __restrict__ w1, const float* __restrict__ w2,
              const float* __restrict__ w3,
              ushort* __restrict__ w1t, ushort* __restrict__ w2t,
              ushort* __restrict__ w3t,
              int n, int bt_tab, int bt_x)
{
    const int b = blockIdx.x;
    if (b < bt_tab) {
        // 2 entries (4 floats) per thread -> uint2 of fp16 pairs
        const int t = b * 256 + threadIdx.x;
        const float4 v = *reinterpret_cast<const float4*>(table + (size_t)t * 4u);
        __half2 ha = __floats2half2_rn(v.x, v.y);
        __half2 hb = __floats2half2_rn(v.z, v.w);
        uint2 o;
        o.x = *reinterpret_cast<uint*>(&ha);
        o.y = *reinterpret_cast<uint*>(&hb);
        *reinterpret_cast<uint2*>(tab16 + (size_t)t * 2u) = o;
    } else if (b < bt_tab + bt_x) {
        const int i = (b - bt_tab) * 256 + threadIdx.x;
        if (i < n)
            x4[i] = make_float4(x[3 * i + 0], x[3 * i + 1], x[3 * i + 2], 0.f);
    } else {
        const int t = (b - bt_tab - bt_x) * 256 + threadIdx.x;
        if (t < 2048) {                       // w1t[n*32+k] = w1[k*64+n]
            const int nn = t >> 5, k = t & 31;
            w1t[t] = f2bf(w1[k * 64 + nn]);
        } else if (t < 2048 + 4096) {         // w2t[n*64+k] = w2[k*64+n]
            const int q = t - 2048;
            const int nn = q >> 6, k = q & 63;
            w2t[q] = f2bf(w2[k * 64 + nn]);
        } else if (t < 2048 + 4096 + 1024) {  // w3t padded to [16][64]
            const int q = t - 6144;
            const int nn = q >> 6, k = q & 63;
            w3t[q] = (nn < 3) ? f2bf(w3[k * 3 + nn]) : (ushort)0;
        }
    }
}

// ---------------- encode: 2 points/thread, fp16 table ----------------
__global__ __launch_bounds__(256, 8)
void ingp_encode2(const float4* __restrict__ x4,
                  const uint* __restrict__ tab16,
                  uint* __restrict__ feat, int n, ResArr res)
{
    const int i0 = (blockIdx.x * 256 + threadIdx.x) * 2;
    const int l = blockIdx.y;
    if (i0 >= n) return;
    const bool two = (i0 + 1 < n);
    const int i1 = two ? i0 + 1 : i0;

    const float rm1 = res.v[l];
    const uint* tl = tab16 + (size_t)l * (size_t)TSIZE;

    // phase 1: indices for both points
    float fx[2], fy[2], fz[2];
    uint h0[2][4], dx[2];
    {
        const float4 xa = x4[i0];
        const float4 xb = x4[i1];
        #pragma unroll
        for (int q = 0; q < 2; ++q) {
            const float4 xp = q ? xb : xa;
            const float px = xp.x * rm1, py = xp.y * rm1, pz = xp.z * rm1;
            const float fpx = floorf(px), fpy = floorf(py), fpz = floorf(pz);
            fx[q] = px - fpx; fy[q] = py - fpy; fz[q] = pz - fpz;
            const uint ix = (uint)fpx, iy = (uint)fpy, iz = (uint)fpz;
            const uint hy0 = iy * PRIME1, hy1 = (iy + 1u) * PRIME1;
            const uint hz0 = iz * PRIME2, hz1 = (iz + 1u) * PRIME2;
            dx[q] = ix ^ (ix + 1u);          // pair distance (1,3,7,...)
            #pragma unroll
            for (int p = 0; p < 4; ++p) {
                const uint hyz = (((p >> 1) & 1) ? hy1 : hy0) ^
                                 ((p & 1) ? hz1 : hz0);
                h0[q][p] = (ix ^ hyz) & TMASK;
            }
        }
    }

    // phase 2: issue ALL 8 block loads (independent, in flight together)
    uint4 blk[2][4];
    #pragma unroll
    for (int q = 0; q < 2; ++q)
        #pragma unroll
        for (int p = 0; p < 4; ++p)
            blk[q][p] = *reinterpret_cast<const uint4*>(tl + (h0[q][p] & ~3u));

    // phase 3+4: per point extract, fixup, accumulate
    uint fo[2];
    #pragma unroll
    for (int q = 0; q < 2; ++q) {
        const bool fast = dx[q] <= 3u;       // pair inside the 16B block
        uint e0[4], e1[4];
        #pragma unroll
        for (int p = 0; p < 4; ++p) {
            e0[p] = pick4(blk[q][p], h0[q][p] & 3u);
            const uint h1v = h0[q][p] ^ dx[q];
            e1[p] = fast ? pick4(blk[q][p], h1v & 3u) : 0u;
        }
        if (!fast) {
            #pragma unroll
            for (int p = 0; p < 4; ++p) e1[p] = tl[h0[q][p] ^ dx[q]];
        }
        const float gx0 = 1.f - fx[q], gx1 = fx[q];
        float a0 = 0.f, a1 = 0.f;
        #pragma unroll
        for (int p = 0; p < 4; ++p) {
            const float wyz = (((p >> 1) & 1) ? fy[q] : 1.f - fy[q]) *
                              ((p & 1) ? fz[q] : 1.f - fz[q]);
            const float w0 = wyz * gx0, w1 = wyz * gx1;
            const float2 c0 = h2f(e0[p]);
            const float2 c1 = h2f(e1[p]);
            a0 = fmaf(w0, c0.x, a0);
            a1 = fmaf(w0, c0.y, a1);
            a0 = fmaf(w1, c1.x, a0);
            a1 = fmaf(w1, c1.y, a1);
        }
        fo[q] = (uint)f2bf(a0) | ((uint)f2bf(a1) << 16);
    }

    if (two) {
        uint2 o; o.x = fo[0]; o.y = fo[1];
        *reinterpret_cast<uint2*>(feat + (size_t)l * n + i0) = o;
    } else {
        feat[(size_t)l * n + i0] = fo[0];
    }
}

// ---------------- Kernel B: MFMA MLP ----------------
__global__ __launch_bounds__(256)
void ingp_mlp_mfma(const uint* __restrict__ feat,
                   const ushort* __restrict__ w1t,
                   const ushort* __restrict__ w2t,
                   const ushort* __restrict__ w3t,
                   const float* __restrict__ b1,
                   const float* __restrict__ b2,
                   const float* __restrict__ b3,
                   float* __restrict__ out, int n)
{
    __shared__ ushort s_h[4][64][72];
    const int tid = threadIdx.x;
    const int wv = tid >> 6;
    const int ln = tid & 63;
    const int lm = ln & 15;
    const int lk = ln >> 4;
    const int base = blockIdx.x * 256 + wv * 64;

    short8v a1[4];
    #pragma unroll
    for (int mt = 0; mt < 4; ++mt) {
        int pt = base + mt * 16 + lm;
        pt = pt < n ? pt : (n - 1);
        union { uint u[4]; short8v v; } c;
        #pragma unroll
        for (int j = 0; j < 4; ++j)
            c.u[j] = feat[(size_t)(lk * 4 + j) * (size_t)n + pt];
        a1[mt] = c.v;
    }

    float4v acc[4][4];
    #pragma unroll
    for (int nt = 0; nt < 4; ++nt) {
        const float bv = b1[nt * 16 + lm];
        #pragma unroll
        for (int mt = 0; mt < 4; ++mt)
            acc[mt][nt] = (float4v){bv, bv, bv, bv};
    }
    #pragma unroll
    for (int nt = 0; nt < 4; ++nt) {
        const short8v bfr = *(const short8v*)(w1t + (nt * 16 + lm) * 32 + lk * 8);
        #pragma unroll
        for (int mt = 0; mt < 4; ++mt)
            acc[mt][nt] = __builtin_amdgcn_mfma_f32_16x16x32_bf16(
                a1[mt], bfr, acc[mt][nt], 0, 0, 0);
    }
    #pragma unroll
    for (int mt = 0; mt < 4; ++mt)
        #pragma unroll
        for (int nt = 0; nt < 4; ++nt)
            #pragma unroll
            for (int r = 0; r < 4; ++r)
                s_h[wv][mt * 16 + lk * 4 + r][nt * 16 + lm] =
                    f2bf(fmaxf(acc[mt][nt][r], 0.f));
    __syncthreads();

    float4v acc2[4][4];
    #pragma unroll
    for (int nt = 0; nt < 4; ++nt) {
        const float bv = b2[nt * 16 + lm];
        #pragma unroll
        for (int mt = 0; mt < 4; ++mt)
            acc2[mt][nt] = (float4v){bv, bv, bv, bv};
    }
    #pragma unroll
    for (int ks = 0; ks < 2; ++ks) {
        short8v a2[4];
        #pragma unroll
        for (int mt = 0; mt < 4; ++mt)
            a2[mt] = *(const short8v*)&s_h[wv][mt * 16 + lm][ks * 32 + lk * 8];
        #pragma unroll
        for (int nt = 0; nt < 4; ++nt) {
            const short8v bfr =
                *(const short8v*)(w2t + (nt * 16 + lm) * 64 + ks * 32 + lk * 8);
            #pragma unroll
            for (int mt = 0; mt < 4; ++mt)
                acc2[mt][nt] = __builtin_amdgcn_mfma_f32_16x16x32_bf16(
                    a2[mt], bfr, acc2[mt][nt], 0, 0, 0);
        }
    }
    __syncthreads();
    #pragma unroll
    for (int mt = 0; mt < 4; ++mt)
        #pragma unroll
        for (int nt = 0; nt < 4; ++nt)
            #pragma unroll
            for (int r = 0; r < 4; ++r)
                s_h[wv][mt * 16 + lk * 4 + r][nt * 16 + lm] =
                    f2bf(fmaxf(acc2[mt][nt][r], 0.f));
    __syncthreads();

    float4v acc3[4];
    const float bv3 = (lm < 3) ? b3[lm] : 0.f;
    #pragma unroll
    for (int mt = 0; mt < 4; ++mt)
        acc3[mt] = (float4v){bv3, bv3, bv3, bv3};
    #pragma unroll
    for (int ks = 0; ks < 2; ++ks) {
        const short8v bfr = *(const short8v*)(w3t + lm * 64 + ks * 32 + lk * 8);
        #pragma unroll
        for (int mt = 0; mt < 4; ++mt) {
            const short8v a3 =
                *(const short8v*)&s_h[wv][mt * 16 + lm][ks * 32 + lk * 8];
            acc3[mt] = __builtin_amdgcn_mfma_f32_16x16x32_bf16(
                a3, bfr, acc3[mt], 0, 0, 0);
        }
    }
    if (lm < 3) {
        #pragma unroll
        for (int mt = 0; mt < 4; ++mt)
            #pragma unroll
            for (int r = 0; r < 4; ++r) {
                const int pt = base + mt * 16 + lk * 4 + r;
                if (pt < n)
                    out[pt * 3 + lm] = 1.f / (1.f + __expf(-acc3[mt][r]));
            }
    }
}

// ---------------- mid fallback: f32 table, paired-corner loads ------------
__global__ __launch_bounds__(256, 8)
void ingp_encode(const float* __restrict__ x,
                 const float* __restrict__ table,
                 uint* __restrict__ feat, int n, ResArr res)
{
    const int i = blockIdx.x * 256 + threadIdx.x;
    const int l = blockIdx.y;
    if (i >= n) return;
    const float xx = x[3 * i + 0], xy = x[3 * i + 1], xz = x[3 * i + 2];
    const float rm1 = res.v[l];
    const float px = xx * rm1, py = xy * rm1, pz = xz * rm1;
    const float fpx = floorf(px), fpy = floorf(py), fpz = floorf(pz);
    const float fx = px - fpx, fy = py - fpy, fz = pz - fpz;
    const uint32_t ix = (uint32_t)fpx, iy = (uint32_t)fpy, iz = (uint32_t)fpz;
    const uint32_t hy0 = iy * PRIME1, hy1 = (iy + 1u) * PRIME1;
    const uint32_t hz0 = iz * PRIME2, hz1 = (iz + 1u) * PRIME2;
    const float* tl = table + (size_t)l * (size_t)TSIZE * 2u;

    uint32_t idx0[4], idx1[4];
    #pragma unroll
    for (int p = 0; p < 4; ++p) {
        const uint32_t bj = (p >> 1) & 1, bk = p & 1;
        const uint32_t hyz = (bj ? hy1 : hy0) ^ (bk ? hz1 : hz0);
        idx0[p] = (ix ^ hyz) & TMASK;
        idx1[p] = ((ix + 1u) ^ hyz) & TMASK;
    }
    float2 c0[4], c1[4];
    if ((ix & 1u) == 0u) {
        #pragma unroll
        for (int p = 0; p < 4; ++p) {
            const uint32_t base = idx0[p] & ~1u;
            const float4 q = *reinterpret_cast<const float4*>(tl + (size_t)base * 2u);
            if (idx0[p] & 1u) { c0[p] = make_float2(q.z, q.w); c1[p] = make_float2(q.x, q.y); }
            else              { c0[p] = make_float2(q.x, q.y); c1[p] = make_float2(q.z, q.w); }
        }
    } else {
        #pragma unroll
        for (int p = 0; p < 4; ++p) {
            c0[p] = *reinterpret_cast<const float2*>(tl + (size_t)idx0[p] * 2u);
            c1[p] = *reinterpret_cast<const float2*>(tl + (size_t)idx1[p] * 2u);
        }
    }
    const float gx0 = 1.f - fx, gx1 = fx;
    float a0 = 0.f, a1 = 0.f;
    #pragma unroll
    for (int p = 0; p < 4; ++p) {
        const int bj = (p >> 1) & 1, bk = p & 1;
        const float wyz = (bj ? fy : 1.f - fy) * (bk ? fz : 1.f - fz);
        const float w0 = wyz * gx0, w1 = wyz * gx1;
        a0 = fmaf(w0, c0[p].x, a0);
        a1 = fmaf(w0, c0[p].y, a1);
        a0 = fmaf(w1, c1[p].x, a0);
        a1 = fmaf(w1, c1[p].y, a1);
    }
    feat[(size_t)l * n + i] = (uint)f2bf(a0) | ((uint)f2bf(a1) << 16);
}

__global__ __launch_bounds__(256)
void ingp_prep(const float* __restrict__ w1, const float* __restrict__ w2,
               const float* __restrict__ w3,
               ushort* __restrict__ w1t, ushort* __restrict__ w2t,
               ushort* __restrict__ w3t)
{
    const int t = blockIdx.x * 256 + threadIdx.x;
    if (t < 2048) {
        const int nn = t >> 5, k = t & 31;
        w1t[t] = f2bf(w1[k * 64 + nn]);
    } else if (t < 2048 + 4096) {
        const int q = t - 2048;
        const int nn = q >> 6, k = q & 63;
        w2t[q] = f2bf(w2[k * 64 + nn]);
    } else if (t < 2048 + 4096 + 1024) {
        const int q = t - 6144;
        const int nn = q >> 6, k = q & 63;
        w3t[q] = (nn < 3) ? f2bf(w3[k * 3 + nn]) : (ushort)0;
    }
}

extern "C" void kernel_launch(void* const* d_in, const int* in_sizes, int n_in,
                              void* d_out, int out_size, void* d_ws, size_t ws_size,
                              hipStream_t stream)
{
    const float* x     = (const float*)d_in[0];
    const float* table = (const float*)d_in[1];
    const float* w1    = (const float*)d_in[2];
    const float* b1    = (const float*)d_in[3];
    const float* w2    = (const float*)d_in[4];
    const float* b2    = (const float*)d_in[5];
    const float* w3    = (const float*)d_in[6];
    const float* b3    = (const float*)d_in[7];
    float* out = (float*)d_out;

    const int n = in_sizes[0] / 3;

    ResArr res;
    {
        const double S = (double)1.3819061f;
        double p = 1.0;
        for (int l = 0; l < LVLS; ++l) {
            res.v[l] = (float)floor(16.0 * p) - 1.0f;
            p *= S;
        }
    }

    const int gb  = (n + 255) / 256;
    const int gb2 = (n + 511) / 512;
    const size_t tab16_bytes = (size_t)LVLS * TSIZE * 4u;         // 33.5 MB
    const size_t feat_bytes  = (size_t)LVLS * (size_t)n * 4u;     // 32 MB
    const size_t x4_bytes    = (size_t)n * 16u;                   // 8 MB

    const size_t off_tab16 = 32768;
    const size_t off_feat  = off_tab16 + tab16_bytes;
    const size_t off_x4    = off_feat + feat_bytes;
    const size_t need_full = off_x4 + x4_bytes;                   // ~74 MB
    const size_t need_mid  = 16384 + feat_bytes;

    if (ws_size >= need_full) {
        ushort* w1t   = (ushort*)d_ws;
        ushort* w2t   = w1t + 2048;
        ushort* w3t   = w2t + 4096;
        uint*   tab16 = (uint*)((char*)d_ws + off_tab16);
        uint*   feat  = (uint*)((char*)d_ws + off_feat);
        float4* x4    = (float4*)((char*)d_ws + off_x4);

        const int bt_tab = (LVLS * (int)TSIZE / 2) / 256;   // 16384 blocks
        const int bt_x   = gb;
        const int bt_w   = 28;
        ingp_pre<<<bt_tab + bt_x + bt_w, 256, 0, stream>>>(
            table, tab16, x, x4, w1, w2, w3, w1t, w2t, w3t, n, bt_tab, bt_x);

        dim3 gridA(gb2, LVLS);
        ingp_encode2<<<gridA, 256, 0, stream>>>(x4, tab16, feat, n, res);
        ingp_mlp_mfma<<<gb, 256, 0, stream>>>(feat, w1t, w2t, w3t,
                                              b1, b2, b3, out, n);
    } else if (ws_size >= need_mid) {
        ushort* w1t = (ushort*)d_ws;
        ushort* w2t = w1t + 2048;
        ushort* w3t = w2t + 4096;
        uint*   feat = (uint*)((char*)d_ws + 16384);
        ingp_prep<<<28, 256, 0, stream>>>(w1, w2, w3, w1t, w2t, w3t);
        dim3 gridA(gb, LVLS);
        ingp_encode<<<gridA, 256, 0, stream>>>(x, table, feat, n, res);
        ingp_mlp_mfma<<<gb, 256, 0, stream>>>(feat, w1t, w2t, w3t,
                                              b1, b2, b3, out, n);
    }
}

// Round 10
// 178.024 us; speedup vs baseline: 1.1778x; 1.1778x over previous
//
#include <hip/hip_runtime.h>
#include <hip/hip_fp16.h>
#include <math.h>

// Instant-NGP forward (round 10 — best-known config, reverted from r9):
//   pre:    ONE kernel: table f32 -> fp16-pair (4B/entry); x -> float4;
//           weights -> bf16 B^T tables.
//   encode: one thread per (point, level), level-major grid (fastest measured:
//           139.5-140 us). dim0 hash prime == 1 => corner pair inside one
//           aligned 16B block (4 fp16-pair entries) for 75% of ix.
//           MSHR*latency bound: ~34M line-requests, ~0.36 lines/cy/CU.
//   mlp:    MFMA bf16 16x16x32; 4 waves/block, 64 points/wave.

constexpr int      LVLS   = 16;
constexpr uint32_t TSIZE  = 1u << 19;
constexpr uint32_t TMASK  = TSIZE - 1u;
constexpr uint32_t PRIME1 = 2654435761u;
constexpr uint32_t PRIME2 = 805459861u;

struct ResArr { float v[LVLS]; };  // res[l] - 1.0f

typedef __attribute__((ext_vector_type(8))) short short8v;  // 8 bf16
typedef __attribute__((ext_vector_type(4))) float float4v;  // MFMA acc

__device__ inline ushort f2bf(float f) {          // RNE f32 -> bf16
    uint u = __float_as_uint(f);
    u += 0x7fffu + ((u >> 16) & 1u);
    return (ushort)(u >> 16);
}

__device__ inline float2 h2f(uint u) {
    __half2 h = *reinterpret_cast<__half2*>(&u);
    return __half22float2(h);
}

__device__ inline uint pick4(const uint4& b, uint j) {
    const uint lo = (j & 1u) ? b.y : b.x;
    const uint hi = (j & 1u) ? b.w : b.z;
    return (j & 2u) ? hi : lo;
}

// ---------------- pre: fp16 table + x pack + weight prep (one kernel) ------
__global__ __launch_bounds__(256)
void ingp_pre(const float* __restrict__ table, uint* __restrict__ tab16,
              const float* __restrict__ x, float4* __restrict__ x4,
              const float* __restrict__ w1, const float* __restrict__ w2,
              const float* __restrict__ w3,
              ushort* __restrict__ w1t, ushort* __restrict__ w2t,
              ushort* __restrict__ w3t,
              int n, int bt_tab, int bt_x)
{
    const int b = blockIdx.x;
    if (b < bt_tab) {
        // 2 entries (4 floats) per thread -> uint2 of fp16 pairs
        const int t = b * 256 + threadIdx.x;
        const float4 v = *reinterpret_cast<const float4*>(table + (size_t)t * 4u);
        __half2 ha = __floats2half2_rn(v.x, v.y);
        __half2 hb = __floats2half2_rn(v.z, v.w);
        uint2 o;
        o.x = *reinterpret_cast<uint*>(&ha);
        o.y = *reinterpret_cast<uint*>(&hb);
        *reinterpret_cast<uint2*>(tab16 + (size_t)t * 2u) = o;
    } else if (b < bt_tab + bt_x) {
        const int i = (b - bt_tab) * 256 + threadIdx.x;
        if (i < n)
            x4[i] = make_float4(x[3 * i + 0], x[3 * i + 1], x[3 * i + 2], 0.f);
    } else {
        const int t = (b - bt_tab - bt_x) * 256 + threadIdx.x;
        if (t < 2048) {                       // w1t[n*32+k] = w1[k*64+n]
            const int nn = t >> 5, k = t & 31;
            w1t[t] = f2bf(w1[k * 64 + nn]);
        } else if (t < 2048 + 4096) {         // w2t[n*64+k] = w2[k*64+n]
            const int q = t - 2048;
            const int nn = q >> 6, k = q & 63;
            w2t[q] = f2bf(w2[k * 64 + nn]);
        } else if (t < 2048 + 4096 + 1024) {  // w3t padded to [16][64]
            const int q = t - 6144;
            const int nn = q >> 6, k = q & 63;
            w3t[q] = (nn < 3) ? f2bf(w3[k * 3 + nn]) : (ushort)0;
        }
    }
}

// ---------------- encode: fp16 table, block-pair loads (r5-exact) ----------
__global__ __launch_bounds__(256, 8)
void ingp_encode_f16(const float4* __restrict__ x4,
                     const uint* __restrict__ tab16,
                     uint* __restrict__ feat, int n, ResArr res)
{
    const int i = blockIdx.x * 256 + threadIdx.x;
    const int l = blockIdx.y;
    if (i >= n) return;

    const float4 xp = x4[i];
    const float rm1 = res.v[l];
    const float px = xp.x * rm1, py = xp.y * rm1, pz = xp.z * rm1;
    const float fpx = floorf(px), fpy = floorf(py), fpz = floorf(pz);
    const float fx = px - fpx, fy = py - fpy, fz = pz - fpz;
    const uint32_t ix = (uint32_t)fpx;
    const uint32_t iy = (uint32_t)fpy;
    const uint32_t iz = (uint32_t)fpz;
    const uint32_t hy0 = iy * PRIME1, hy1 = (iy + 1u) * PRIME1;
    const uint32_t hz0 = iz * PRIME2, hz1 = (iz + 1u) * PRIME2;
    const uint* tl = tab16 + (size_t)l * (size_t)TSIZE;

    uint32_t h0[4], h1[4];
    #pragma unroll
    for (int p = 0; p < 4; ++p) {
        const uint32_t bj = (p >> 1) & 1, bk = p & 1;
        const uint32_t hyz = (bj ? hy1 : hy0) ^ (bk ? hz1 : hz0);
        h0[p] = (ix ^ hyz) & TMASK;
        h1[p] = ((ix + 1u) ^ hyz) & TMASK;
    }

    uint e0[4], e1[4];
    if ((ix & 3u) != 3u) {
        // pair distance d = ix^(ix+1) is 1 or 3 -> both corners inside one
        // aligned 4-entry (16B) block.
        #pragma unroll
        for (int p = 0; p < 4; ++p) {
            const uint32_t base = h0[p] & ~3u;
            const uint4 blk = *reinterpret_cast<const uint4*>(tl + base);
            e0[p] = pick4(blk, h0[p] & 3u);
            e1[p] = pick4(blk, h1[p] & 3u);
        }
    } else {
        #pragma unroll
        for (int p = 0; p < 4; ++p) {
            e0[p] = tl[h0[p]];
            e1[p] = tl[h1[p]];
        }
    }

    const float gx0 = 1.f - fx, gx1 = fx;
    float a0 = 0.f, a1 = 0.f;
    #pragma unroll
    for (int p = 0; p < 4; ++p) {
        const int bj = (p >> 1) & 1, bk = p & 1;
        const float wyz = (bj ? fy : 1.f - fy) * (bk ? fz : 1.f - fz);
        const float w0 = wyz * gx0, w1 = wyz * gx1;
        const float2 c0 = h2f(e0[p]);
        const float2 c1 = h2f(e1[p]);
        a0 = fmaf(w0, c0.x, a0);
        a1 = fmaf(w0, c0.y, a1);
        a0 = fmaf(w1, c1.x, a0);
        a1 = fmaf(w1, c1.y, a1);
    }
    feat[(size_t)l * n + i] = (uint)f2bf(a0) | ((uint)f2bf(a1) << 16);
}

// ---------------- Kernel B: MFMA MLP ----------------
__global__ __launch_bounds__(256)
void ingp_mlp_mfma(const uint* __restrict__ feat,
                   const ushort* __restrict__ w1t,
                   const ushort* __restrict__ w2t,
                   const ushort* __restrict__ w3t,
                   const float* __restrict__ b1,
                   const float* __restrict__ b2,
                   const float* __restrict__ b3,
                   float* __restrict__ out, int n)
{
    __shared__ ushort s_h[4][64][72];
    const int tid = threadIdx.x;
    const int wv = tid >> 6;
    const int ln = tid & 63;
    const int lm = ln & 15;
    const int lk = ln >> 4;
    const int base = blockIdx.x * 256 + wv * 64;

    short8v a1[4];
    #pragma unroll
    for (int mt = 0; mt < 4; ++mt) {
        int pt = base + mt * 16 + lm;
        pt = pt < n ? pt : (n - 1);
        union { uint u[4]; short8v v; } c;
        #pragma unroll
        for (int j = 0; j < 4; ++j)
            c.u[j] = feat[(size_t)(lk * 4 + j) * (size_t)n + pt];
        a1[mt] = c.v;
    }

    float4v acc[4][4];
    #pragma unroll
    for (int nt = 0; nt < 4; ++nt) {
        const float bv = b1[nt * 16 + lm];
        #pragma unroll
        for (int mt = 0; mt < 4; ++mt)
            acc[mt][nt] = (float4v){bv, bv, bv, bv};
    }
    #pragma unroll
    for (int nt = 0; nt < 4; ++nt) {
        const short8v bfr = *(const short8v*)(w1t + (nt * 16 + lm) * 32 + lk * 8);
        #pragma unroll
        for (int mt = 0; mt < 4; ++mt)
            acc[mt][nt] = __builtin_amdgcn_mfma_f32_16x16x32_bf16(
                a1[mt], bfr, acc[mt][nt], 0, 0, 0);
    }
    #pragma unroll
    for (int mt = 0; mt < 4; ++mt)
        #pragma unroll
        for (int nt = 0; nt < 4; ++nt)
            #pragma unroll
            for (int r = 0; r < 4; ++r)
                s_h[wv][mt * 16 + lk * 4 + r][nt * 16 + lm] =
                    f2bf(fmaxf(acc[mt][nt][r], 0.f));
    __syncthreads();

    float4v acc2[4][4];
    #pragma unroll
    for (int nt = 0; nt < 4; ++nt) {
        const float bv = b2[nt * 16 + lm];
        #pragma unroll
        for (int mt = 0; mt < 4; ++mt)
            acc2[mt][nt] = (float4v){bv, bv, bv, bv};
    }
    #pragma unroll
    for (int ks = 0; ks < 2; ++ks) {
        short8v a2[4];
        #pragma unroll
        for (int mt = 0; mt < 4; ++mt)
            a2[mt] = *(const short8v*)&s_h[wv][mt * 16 + lm][ks * 32 + lk * 8];
        #pragma unroll
        for (int nt = 0; nt < 4; ++nt) {
            const short8v bfr =
                *(const short8v*)(w2t + (nt * 16 + lm) * 64 + ks * 32 + lk * 8);
            #pragma unroll
            for (int mt = 0; mt < 4; ++mt)
                acc2[mt][nt] = __builtin_amdgcn_mfma_f32_16x16x32_bf16(
                    a2[mt], bfr, acc2[mt][nt], 0, 0, 0);
        }
    }
    __syncthreads();
    #pragma unroll
    for (int mt = 0; mt < 4; ++mt)
        #pragma unroll
        for (int nt = 0; nt < 4; ++nt)
            #pragma unroll
            for (int r = 0; r < 4; ++r)
                s_h[wv][mt * 16 + lk * 4 + r][nt * 16 + lm] =
                    f2bf(fmaxf(acc2[mt][nt][r], 0.f));
    __syncthreads();

    float4v acc3[4];
    const float bv3 = (lm < 3) ? b3[lm] : 0.f;
    #pragma unroll
    for (int mt = 0; mt < 4; ++mt)
        acc3[mt] = (float4v){bv3, bv3, bv3, bv3};
    #pragma unroll
    for (int ks = 0; ks < 2; ++ks) {
        const short8v bfr = *(const short8v*)(w3t + lm * 64 + ks * 32 + lk * 8);
        #pragma unroll
        for (int mt = 0; mt < 4; ++mt) {
            const short8v a3 =
                *(const short8v*)&s_h[wv][mt * 16 + lm][ks * 32 + lk * 8];
            acc3[mt] = __builtin_amdgcn_mfma_f32_16x16x32_bf16(
                a3, bfr, acc3[mt], 0, 0, 0);
        }
    }
    if (lm < 3) {
        #pragma unroll
        for (int mt = 0; mt < 4; ++mt)
            #pragma unroll
            for (int r = 0; r < 4; ++r) {
                const int pt = base + mt * 16 + lk * 4 + r;
                if (pt < n)
                    out[pt * 3 + lm] = 1.f / (1.f + __expf(-acc3[mt][r]));
            }
    }
}

// ---------------- fallback: f32 table, paired-corner loads ------------
__global__ __launch_bounds__(256, 8)
void ingp_encode(const float* __restrict__ x,
                 const float* __restrict__ table,
                 uint* __restrict__ feat, int n, ResArr res)
{
    const int i = blockIdx.x * 256 + threadIdx.x;
    const int l = blockIdx.y;
    if (i >= n) return;
    const float xx = x[3 * i + 0], xy = x[3 * i + 1], xz = x[3 * i + 2];
    const float rm1 = res.v[l];
    const float px = xx * rm1, py = xy * rm1, pz = xz * rm1;
    const float fpx = floorf(px), fpy = floorf(py), fpz = floorf(pz);
    const float fx = px - fpx, fy = py - fpy, fz = pz - fpz;
    const uint32_t ix = (uint32_t)fpx, iy = (uint32_t)fpy, iz = (uint32_t)fpz;
    const uint32_t hy0 = iy * PRIME1, hy1 = (iy + 1u) * PRIME1;
    const uint32_t hz0 = iz * PRIME2, hz1 = (iz + 1u) * PRIME2;
    const float* tl = table + (size_t)l * (size_t)TSIZE * 2u;

    uint32_t idx0[4], idx1[4];
    #pragma unroll
    for (int p = 0; p < 4; ++p) {
        const uint32_t bj = (p >> 1) & 1, bk = p & 1;
        const uint32_t hyz = (bj ? hy1 : hy0) ^ (bk ? hz1 : hz0);
        idx0[p] = (ix ^ hyz) & TMASK;
        idx1[p] = ((ix + 1u) ^ hyz) & TMASK;
    }
    float2 c0[4], c1[4];
    if ((ix & 1u) == 0u) {
        #pragma unroll
        for (int p = 0; p < 4; ++p) {
            const uint32_t base = idx0[p] & ~1u;
            const float4 q = *reinterpret_cast<const float4*>(tl + (size_t)base * 2u);
            if (idx0[p] & 1u) { c0[p] = make_float2(q.z, q.w); c1[p] = make_float2(q.x, q.y); }
            else              { c0[p] = make_float2(q.x, q.y); c1[p] = make_float2(q.z, q.w); }
        }
    } else {
        #pragma unroll
        for (int p = 0; p < 4; ++p) {
            c0[p] = *reinterpret_cast<const float2*>(tl + (size_t)idx0[p] * 2u);
            c1[p] = *reinterpret_cast<const float2*>(tl + (size_t)idx1[p] * 2u);
        }
    }
    const float gx0 = 1.f - fx, gx1 = fx;
    float a0 = 0.f, a1 = 0.f;
    #pragma unroll
    for (int p = 0; p < 4; ++p) {
        const int bj = (p >> 1) & 1, bk = p & 1;
        const float wyz = (bj ? fy : 1.f - fy) * (bk ? fz : 1.f - fz);
        const float w0 = wyz * gx0, w1 = wyz * gx1;
        a0 = fmaf(w0, c0[p].x, a0);
        a1 = fmaf(w0, c0[p].y, a1);
        a0 = fmaf(w1, c1[p].x, a0);
        a1 = fmaf(w1, c1[p].y, a1);
    }
    feat[(size_t)l * n + i] = (uint)f2bf(a0) | ((uint)f2bf(a1) << 16);
}

__global__ __launch_bounds__(256)
void ingp_prep(const float* __restrict__ w1, const float* __restrict__ w2,
               const float* __restrict__ w3,
               ushort* __restrict__ w1t, ushort* __restrict__ w2t,
               ushort* __restrict__ w3t)
{
    const int t = blockIdx.x * 256 + threadIdx.x;
    if (t < 2048) {
        const int nn = t >> 5, k = t & 31;
        w1t[t] = f2bf(w1[k * 64 + nn]);
    } else if (t < 2048 + 4096) {
        const int q = t - 2048;
        const int nn = q >> 6, k = q & 63;
        w2t[q] = f2bf(w2[k * 64 + nn]);
    } else if (t < 2048 + 4096 + 1024) {
        const int q = t - 6144;
        const int nn = q >> 6, k = q & 63;
        w3t[q] = (nn < 3) ? f2bf(w3[k * 3 + nn]) : (ushort)0;
    }
}

extern "C" void kernel_launch(void* const* d_in, const int* in_sizes, int n_in,
                              void* d_out, int out_size, void* d_ws, size_t ws_size,
                              hipStream_t stream)
{
    const float* x     = (const float*)d_in[0];
    const float* table = (const float*)d_in[1];
    const float* w1    = (const float*)d_in[2];
    const float* b1    = (const float*)d_in[3];
    const float* w2    = (const float*)d_in[4];
    const float* b2    = (const float*)d_in[5];
    const float* w3    = (const float*)d_in[6];
    const float* b3    = (const float*)d_in[7];
    float* out = (float*)d_out;

    const int n = in_sizes[0] / 3;

    ResArr res;
    {
        const double S = (double)1.3819061f;
        double p = 1.0;
        for (int l = 0; l < LVLS; ++l) {
            res.v[l] = (float)floor(16.0 * p) - 1.0f;
            p *= S;
        }
    }

    const int gb = (n + 255) / 256;
    const size_t tab16_bytes = (size_t)LVLS * TSIZE * 4u;         // 33.5 MB
    const size_t feat_bytes  = (size_t)LVLS * (size_t)n * 4u;     // 32 MB
    const size_t x4_bytes    = (size_t)n * 16u;                   // 8 MB

    const size_t off_tab16 = 32768;
    const size_t off_feat  = off_tab16 + tab16_bytes;
    const size_t off_x4    = off_feat + feat_bytes;
    const size_t need_full = off_x4 + x4_bytes;                   // ~74 MB
    const size_t need_mid  = 16384 + feat_bytes;

    if (ws_size >= need_full) {
        ushort* w1t   = (ushort*)d_ws;
        ushort* w2t   = w1t + 2048;
        ushort* w3t   = w2t + 4096;
        uint*   tab16 = (uint*)((char*)d_ws + off_tab16);
        uint*   feat  = (uint*)((char*)d_ws + off_feat);
        float4* x4    = (float4*)((char*)d_ws + off_x4);

        const int bt_tab = (LVLS * (int)TSIZE / 2) / 256;   // 16384 blocks
        const int bt_x   = gb;
        const int bt_w   = 28;
        ingp_pre<<<bt_tab + bt_x + bt_w, 256, 0, stream>>>(
            table, tab16, x, x4, w1, w2, w3, w1t, w2t, w3t, n, bt_tab, bt_x);

        dim3 gridA(gb, LVLS);
        ingp_encode_f16<<<gridA, 256, 0, stream>>>(x4, tab16, feat, n, res);
        ingp_mlp_mfma<<<gb, 256, 0, stream>>>(feat, w1t, w2t, w3t,
                                              b1, b2, b3, out, n);
    } else if (ws_size >= need_mid) {
        ushort* w1t = (ushort*)d_ws;
        ushort* w2t = w1t + 2048;
        ushort* w3t = w2t + 4096;
        uint*   feat = (uint*)((char*)d_ws + 16384);
        ingp_prep<<<28, 256, 0, stream>>>(w1, w2, w3, w1t, w2t, w3t);
        dim3 gridA(gb, LVLS);
        ingp_encode<<<gridA, 256, 0, stream>>>(x, table, feat, n, res);
        ingp_mlp_mfma<<<gb, 256, 0, stream>>>(feat, w1t, w2t, w3t,
                                              b1, b2, b3, out, n);
    }
}